// Round 14
// baseline (362.719 us; speedup 1.0000x reference)
//
#include <hip/hip_runtime.h>
#include <hip/hip_bf16.h>

// Model dims (fixed by the reference)
#define R_ 64
#define S_ 32
#define T_ 50
#define E_ 512
#define U_ 20
#define D_ 532   // E + U
#define L_ 9
#define NSENT (R_ * S_)   // 2048

#define PCHUNK 128
#define NCG 5
#define NKG 5

// ===== INSTRUMENTATION (this round only): idempotent in-kernel repeats so the
// real kernels rise above the harness's 57us poison fills in the top-5 table.
// total = 8*A + 16*G1 + G2 + D + ovh;  baseline(R6, all x1) = 81us  -> solvable.
#define REP_A  8
#define REP_G1 16

typedef __attribute__((ext_vector_type(8))) short bf16x8;
typedef __attribute__((ext_vector_type(4))) float f32x4;

__device__ __forceinline__ float selu_f(float x) {
    const float scale = 1.0507009873554805f;
    const float alpha = 1.6732632423543772f;
    return x > 0.0f ? scale * x : scale * alpha * expm1f(x);
}

// Kernel A (fused): blocks [0,2048) = per-sentence masked token-mean -> bf16.
// blocks [2048,2560) = transpose-convert {w_sent, w_rev} -> bf16 wT[z][n][k].
__global__ __launch_bounds__(256) void k_fused_A(
        const int* __restrict__ inputs,
        const float* __restrict__ emb,
        const float* __restrict__ w_sent,
        const float* __restrict__ w_rev,
        __hip_bfloat16* __restrict__ sent_bf,
        __hip_bfloat16* __restrict__ wT,
        float* __restrict__ smask,
        int* __restrict__ dcount)
{
    const int tid = threadIdx.x;

    if (blockIdx.x >= NSENT) {
        __shared__ float tile[32][33];
        const int b = blockIdx.x - NSENT;
        const int z = b >> 8;
        const float* w = z ? w_rev : w_sent;
        __hip_bfloat16* o = wT + (size_t)z * E_ * E_;
        const int bb = b & 255;
        const int tx = tid & 31, ty = tid >> 5;
        const int k0 = (bb >> 4) * 32, n0 = (bb & 15) * 32;
        for (int rep = 0; rep < REP_A; ++rep) {
            asm volatile("" ::: "memory");
            #pragma unroll
            for (int i = 0; i < 4; ++i)
                tile[ty + 8 * i][tx] = w[(size_t)(k0 + ty + 8 * i) * E_ + n0 + tx];
            __syncthreads();
            #pragma unroll
            for (int i = 0; i < 4; ++i)
                o[(size_t)(n0 + ty + 8 * i) * E_ + k0 + tx] =
                    __float2bfloat16(tile[tx][ty + 8 * i]);
            __syncthreads();
        }
        return;
    }

    if (blockIdx.x == 0 && tid == 0) *dcount = 0;

    const int sid = blockIdx.x;
    const int base = sid * T_;
    for (int rep = 0; rep < REP_A; ++rep) {
        asm volatile("" ::: "memory");
        float2 acc = {0.f, 0.f};
        int cnt = 0;
        for (int t = 0; t < T_; ++t) {
            const int tok = inputs[base + t];
            const float m = (tok != 0) ? 1.0f : 0.0f;
            cnt += (tok != 0);
            const float2 v = ((const float2*)(emb + (size_t)tok * E_))[tid];
            acc.x = fmaf(v.x, m, acc.x);
            acc.y = fmaf(v.y, m, acc.y);
        }
        const float inv = 1.0f / fmaxf((float)cnt, 1.0f);
        __hip_bfloat162 h2;
        h2.x = __float2bfloat16(acc.x * inv);
        h2.y = __float2bfloat16(acc.y * inv);
        ((__hip_bfloat162*)(sent_bf + (size_t)sid * E_))[tid] = h2;
        if (tid == 0) smask[sid] = (cnt > 0) ? 1.0f : 0.0f;
    }
}

// Kernel G1: sent GEMM + masked-mean epilogue. grid (8,32), block 256.
__global__ __launch_bounds__(256) void k_gemm_sent_mean(
        const __hip_bfloat16* __restrict__ A,
        const __hip_bfloat16* __restrict__ Bt,
        const float* __restrict__ bias,
        const float* __restrict__ smask,
        __hip_bfloat16* __restrict__ mrev)
{
    __shared__ short As[64][40];
    __shared__ short Bs[64][40];
    const int tid  = threadIdx.x;
    const int wid  = tid >> 6;
    const int lane = tid & 63;
    const int wm = wid >> 1, wn = wid & 1;
    const int bm = blockIdx.y * 64, bn = blockIdx.x * 64;
    const int srow = tid >> 2;
    const int soff = (tid & 3) * 8;
    const short* Ag  = (const short*)A;
    const short* Btg = (const short*)Bt;
    const int fr = lane & 15;
    const int kg = (lane >> 4) * 8;
    const int rq = (lane >> 4) * 4;

    for (int rep = 0; rep < REP_G1; ++rep) {
        asm volatile("" ::: "memory");
        f32x4 acc[2][2];
        #pragma unroll
        for (int i = 0; i < 2; ++i)
            #pragma unroll
            for (int j = 0; j < 2; ++j) acc[i][j] = (f32x4){0.f, 0.f, 0.f, 0.f};

        for (int k0 = 0; k0 < E_; k0 += 32) {
            __syncthreads();
            *(bf16x8*)&As[srow][soff] = *(const bf16x8*)&Ag[(size_t)(bm + srow) * E_ + k0 + soff];
            *(bf16x8*)&Bs[srow][soff] = *(const bf16x8*)&Btg[(size_t)(bn + srow) * E_ + k0 + soff];
            __syncthreads();
            bf16x8 af0 = *(const bf16x8*)&As[wm * 32 + fr][kg];
            bf16x8 af1 = *(const bf16x8*)&As[wm * 32 + 16 + fr][kg];
            bf16x8 bf0 = *(const bf16x8*)&Bs[wn * 32 + fr][kg];
            bf16x8 bf1 = *(const bf16x8*)&Bs[wn * 32 + 16 + fr][kg];
            acc[0][0] = __builtin_amdgcn_mfma_f32_16x16x32_bf16(af0, bf0, acc[0][0], 0, 0, 0);
            acc[0][1] = __builtin_amdgcn_mfma_f32_16x16x32_bf16(af0, bf1, acc[0][1], 0, 0, 0);
            acc[1][0] = __builtin_amdgcn_mfma_f32_16x16x32_bf16(af1, bf0, acc[1][0], 0, 0, 0);
            acc[1][1] = __builtin_amdgcn_mfma_f32_16x16x32_bf16(af1, bf1, acc[1][1], 0, 0, 0);
        }

        float m[2][4];
        float msum = 0.f;
        #pragma unroll
        for (int fm = 0; fm < 2; ++fm)
            #pragma unroll
            for (int j = 0; j < 4; ++j) {
                m[fm][j] = smask[bm + wm * 32 + fm * 16 + rq + j];
                msum += m[fm][j];
            }
        float colsum[2];
        #pragma unroll
        for (int fn = 0; fn < 2; ++fn) {
            const float bv = bias[bn + wn * 32 + fn * 16 + fr];
            float s = 0.f;
            #pragma unroll
            for (int fm = 0; fm < 2; ++fm)
                #pragma unroll
                for (int j = 0; j < 4; ++j)
                    s = fmaf(selu_f(acc[fm][fn][j] + bv), m[fm][j], s);
            colsum[fn] = s;
        }
        #pragma unroll
        for (int fn = 0; fn < 2; ++fn) {
            colsum[fn] += __shfl_xor(colsum[fn], 16, 64);
            colsum[fn] += __shfl_xor(colsum[fn], 32, 64);
        }
        msum += __shfl_xor(msum, 16, 64);
        msum += __shfl_xor(msum, 32, 64);
        const float inv = 1.0f / fmaxf(msum, 1.0f);
        if (lane < 16) {
            const int g = 2 * blockIdx.y + wm;
            #pragma unroll
            for (int fn = 0; fn < 2; ++fn)
                mrev[(size_t)g * E_ + bn + wn * 32 + fn * 16 + fr] =
                    __float2bfloat16(colsum[fn] * inv);
        }
        __syncthreads();
    }
}

// Kernel G2: rev GEMM -> p_batch cols 0..511; block 0 also user-feat cols.
__global__ __launch_bounds__(256) void k_gemm_rev(
        const __hip_bfloat16* __restrict__ A,
        const __hip_bfloat16* __restrict__ Bt,
        const float* __restrict__ bias,
        const float* __restrict__ user_feats,
        const float* __restrict__ user_w,
        float* __restrict__ p_batch)
{
    __shared__ short As[64][40];
    __shared__ short Bs[64][40];
    const int tid  = threadIdx.x;
    const int wid  = tid >> 6;
    const int lane = tid & 63;
    const int wm = wid >> 1, wn = wid & 1;
    const int bn = blockIdx.x * 64;

    if (blockIdx.x == 0 && tid < 64) {
        const int r = tid;
        float ss = 0.f;
        #pragma unroll
        for (int j = 0; j < U_; ++j) {
            const float u = user_feats[r * U_ + j];
            ss = fmaf(u, u, ss);
        }
        const float nrm = fmaxf(sqrtf(ss), 1e-12f);
        #pragma unroll
        for (int j = 0; j < U_; ++j)
            p_batch[(size_t)r * D_ + E_ + j] = user_feats[r * U_ + j] / nrm * user_w[j];
    }

    const int srow = tid >> 2;
    const int soff = (tid & 3) * 8;
    const short* Ag  = (const short*)A;
    const short* Btg = (const short*)Bt;

    f32x4 acc[2][2];
    #pragma unroll
    for (int i = 0; i < 2; ++i)
        #pragma unroll
        for (int j = 0; j < 2; ++j) acc[i][j] = (f32x4){0.f, 0.f, 0.f, 0.f};

    const int fr = lane & 15;
    const int kg = (lane >> 4) * 8;

    for (int k0 = 0; k0 < E_; k0 += 32) {
        __syncthreads();
        *(bf16x8*)&As[srow][soff] = *(const bf16x8*)&Ag[(size_t)srow * E_ + k0 + soff];
        *(bf16x8*)&Bs[srow][soff] = *(const bf16x8*)&Btg[(size_t)(bn + srow) * E_ + k0 + soff];
        __syncthreads();
        bf16x8 af0 = *(const bf16x8*)&As[wm * 32 + fr][kg];
        bf16x8 af1 = *(const bf16x8*)&As[wm * 32 + 16 + fr][kg];
        bf16x8 bf0 = *(const bf16x8*)&Bs[wn * 32 + fr][kg];
        bf16x8 bf1 = *(const bf16x8*)&Bs[wn * 32 + 16 + fr][kg];
        acc[0][0] = __builtin_amdgcn_mfma_f32_16x16x32_bf16(af0, bf0, acc[0][0], 0, 0, 0);
        acc[0][1] = __builtin_amdgcn_mfma_f32_16x16x32_bf16(af0, bf1, acc[0][1], 0, 0, 0);
        acc[1][0] = __builtin_amdgcn_mfma_f32_16x16x32_bf16(af1, bf0, acc[1][0], 0, 0, 0);
        acc[1][1] = __builtin_amdgcn_mfma_f32_16x16x32_bf16(af1, bf1, acc[1][1], 0, 0, 0);
    }

    const int rq = (lane >> 4) * 4;
    #pragma unroll
    for (int fm = 0; fm < 2; ++fm) {
        #pragma unroll
        for (int fn = 0; fn < 2; ++fn) {
            const int col = bn + wn * 32 + fn * 16 + fr;
            const float bv = bias[col];
            #pragma unroll
            for (int j = 0; j < 4; ++j) {
                const int row = wm * 32 + fm * 16 + rq + j;
                p_batch[(size_t)row * D_ + col] = selu_f(acc[fm][fn][j] + bv);
            }
        }
    }
}

// Kernel D (fused): partial GEMV tiles; last block finalizes. grid (5,5).
__global__ __launch_bounds__(256) void k_prod_fused(
        const float* __restrict__ p_batch,
        const float* __restrict__ w_prod,
        const float* __restrict__ b_prod,
        const float* __restrict__ w_pff,
        const float* __restrict__ b_pff,
        const float* __restrict__ w_rff,
        const float* __restrict__ b_rff,
        float* __restrict__ part,
        int* __restrict__ dcount,
        float* __restrict__ out_p,
        float* __restrict__ out_r)
{
    __shared__ float pbar[PCHUNK];
    __shared__ float red[2][PCHUNK];
    const int cg = blockIdx.x, kg = blockIdx.y;
    const int tid = threadIdx.x;
    const int cl = tid & (PCHUNK - 1);
    const int h  = tid >> 7;
    const int k0 = kg * PCHUNK;
    const int klen = min(PCHUNK, D_ - k0);

    if (cl < klen) {
        float s = 0.f;
        #pragma unroll 8
        for (int r = h * 32; r < h * 32 + 32; ++r)
            s += p_batch[(size_t)r * D_ + k0 + cl];
        red[h][cl] = s;
    }
    __syncthreads();
    if (h == 0 && cl < klen) pbar[cl] = (red[0][cl] + red[1][cl]) * (1.0f / 64.0f);
    __syncthreads();

    const int c = cg * PCHUNK + cl;
    float acc = 0.f;
    if (c < D_) {
        const int jb = h * 64;
        const int je = min(jb + 64, klen);
        for (int j = jb; j < je; ++j)
            acc = fmaf(pbar[j], w_prod[(size_t)(k0 + j) * D_ + c], acc);
    }
    red[h][cl] = acc;
    __syncthreads();
    if (h == 0 && c < D_) part[kg * D_ + c] = red[0][cl] + red[1][cl];

    __threadfence();
    __shared__ int is_last;
    if (tid == 0) is_last = (atomicAdd(dcount, 1) == NCG * NKG - 1);
    __syncthreads();
    if (!is_last) return;
    __threadfence();

    __shared__ float hn[D_];
    __shared__ float rred[4][64];
    for (int cc = tid; cc < D_; cc += 256) {
        float s = b_prod[cc];
        #pragma unroll
        for (int g = 0; g < NKG; ++g) s += part[g * D_ + cc];
        hn[cc] = selu_f(s);
    }
    __syncthreads();
    if (tid < L_) {
        float a = 0.f;
        for (int k = 0; k < D_; ++k) a = fmaf(hn[k], w_pff[k * L_ + tid], a);
        out_p[tid] = selu_f(a + b_pff[tid]);
    }
    {
        const int r = tid & 63, q = tid >> 6;
        float pr = 0.f;
        for (int k = q * 133; k < (q + 1) * 133; ++k)
            pr = fmaf(p_batch[(size_t)r * D_ + k], w_rff[k], pr);
        rred[q][r] = pr;
    }
    __syncthreads();
    if (tid < 64)
        out_r[tid] = selu_f(rred[0][tid] + rred[1][tid] + rred[2][tid] + rred[3][tid]
                            + b_rff[0]);
}

extern "C" void kernel_launch(void* const* d_in, const int* in_sizes, int n_in,
                              void* d_out, int out_size, void* d_ws, size_t ws_size,
                              hipStream_t stream) {
    const int*   inputs     = (const int*)  d_in[0];
    const float* user_feats = (const float*)d_in[1];
    const float* emb        = (const float*)d_in[2];
    const float* w_sent     = (const float*)d_in[3];
    const float* b_sent     = (const float*)d_in[4];
    const float* w_rev      = (const float*)d_in[5];
    const float* b_rev      = (const float*)d_in[6];
    const float* w_prod     = (const float*)d_in[7];
    const float* b_prod     = (const float*)d_in[8];
    const float* w_rff      = (const float*)d_in[9];
    const float* b_rff      = (const float*)d_in[10];
    const float* w_pff      = (const float*)d_in[11];
    const float* b_pff      = (const float*)d_in[12];
    const float* user_w     = (const float*)d_in[13];
    float* out = (float*)d_out;

    float* ws = (float*)d_ws;
    __hip_bfloat16* sent_bf = (__hip_bfloat16*)(ws);
    __hip_bfloat16* wT      = (__hip_bfloat16*)(ws + 524288);
    __hip_bfloat16* mrev    = (__hip_bfloat16*)(ws + 786432);
    float* smask   = ws + 802816;
    float* p_batch = ws + 804864;
    float* part    = ws + 838912;
    int*   dcount  = (int*)(ws + 841600);

    k_fused_A<<<NSENT + 512, 256, 0, stream>>>(inputs, emb, w_sent, w_rev,
                                               sent_bf, wT, smask, dcount);
    k_gemm_sent_mean<<<dim3(E_ / 64, NSENT / 64), 256, 0, stream>>>(
        sent_bf, wT, b_sent, smask, mrev);
    k_gemm_rev<<<dim3(E_ / 64, 1), 256, 0, stream>>>(
        mrev, wT + (size_t)E_ * E_, b_rev, user_feats, user_w, p_batch);
    k_prod_fused<<<dim3(NCG, NKG), 256, 0, stream>>>(
        p_batch, w_prod, b_prod, w_pff, b_pff, w_rff, b_rff,
        part, dcount, out, out + L_);
}

// Round 15
// 88.604 us; speedup vs baseline: 4.0937x; 4.0937x over previous
//
#include <hip/hip_runtime.h>
#include <hip/hip_bf16.h>

// Model dims (fixed by the reference)
#define R_ 64
#define S_ 32
#define T_ 50
#define E_ 512
#define U_ 20
#define D_ 532   // E + U
#define L_ 9
#define NSENT (R_ * S_)   // 2048

#define PCHUNK 128
#define NCG 5
#define NKG 5

typedef __attribute__((ext_vector_type(8))) short bf16x8;
typedef __attribute__((ext_vector_type(4))) float f32x4;

__device__ __forceinline__ float selu_f(float x) {
    const float scale = 1.0507009873554805f;
    const float alpha = 1.6732632423543772f;
    return x > 0.0f ? scale * x : scale * alpha * expm1f(x);
}

// Kernel A (fused): blocks [0,2048) = per-sentence masked token-mean -> bf16.
// blocks [2048,2560) = transpose-convert {w_sent, w_rev} -> bf16 wT[z][n][k].
// block 0 zero-inits the D-stage completion counter.
// Measured R14: ~29.5 us, 96 MB L2-miss traffic/pass (random-gather service bound).
__global__ __launch_bounds__(256) void k_fused_A(
        const int* __restrict__ inputs,
        const float* __restrict__ emb,
        const float* __restrict__ w_sent,
        const float* __restrict__ w_rev,
        __hip_bfloat16* __restrict__ sent_bf,
        __hip_bfloat16* __restrict__ wT,
        float* __restrict__ smask,
        int* __restrict__ dcount)
{
    const int tid = threadIdx.x;

    if (blockIdx.x >= NSENT) {
        __shared__ float tile[32][33];
        const int b = blockIdx.x - NSENT;
        const int z = b >> 8;
        const float* w = z ? w_rev : w_sent;
        __hip_bfloat16* o = wT + (size_t)z * E_ * E_;
        const int bb = b & 255;
        const int tx = tid & 31, ty = tid >> 5;
        const int k0 = (bb >> 4) * 32, n0 = (bb & 15) * 32;
        #pragma unroll
        for (int i = 0; i < 4; ++i)
            tile[ty + 8 * i][tx] = w[(size_t)(k0 + ty + 8 * i) * E_ + n0 + tx];
        __syncthreads();
        #pragma unroll
        for (int i = 0; i < 4; ++i)
            o[(size_t)(n0 + ty + 8 * i) * E_ + k0 + tx] = __float2bfloat16(tile[tx][ty + 8 * i]);
        return;
    }

    if (blockIdx.x == 0 && tid == 0) *dcount = 0;

    const int sid = blockIdx.x;
    const int base = sid * T_;
    float2 acc = {0.f, 0.f};
    int cnt = 0;
    for (int t = 0; t < T_; ++t) {
        const int tok = inputs[base + t];
        const float m = (tok != 0) ? 1.0f : 0.0f;
        cnt += (tok != 0);
        const float2 v = ((const float2*)(emb + (size_t)tok * E_))[tid];
        acc.x = fmaf(v.x, m, acc.x);
        acc.y = fmaf(v.y, m, acc.y);
    }
    const float inv = 1.0f / fmaxf((float)cnt, 1.0f);
    __hip_bfloat162 h2;
    h2.x = __float2bfloat16(acc.x * inv);
    h2.y = __float2bfloat16(acc.y * inv);
    ((__hip_bfloat162*)(sent_bf + (size_t)sid * E_))[tid] = h2;
    if (tid == 0) smask[sid] = (cnt > 0) ? 1.0f : 0.0f;
}

// Kernel G1: sent GEMM + masked-mean epilogue. grid (8,32). Measured: ~5 us.
__global__ __launch_bounds__(256) void k_gemm_sent_mean(
        const __hip_bfloat16* __restrict__ A,
        const __hip_bfloat16* __restrict__ Bt,
        const float* __restrict__ bias,
        const float* __restrict__ smask,
        __hip_bfloat16* __restrict__ mrev)
{
    __shared__ short As[64][40];
    __shared__ short Bs[64][40];
    const int tid  = threadIdx.x;
    const int wid  = tid >> 6;
    const int lane = tid & 63;
    const int wm = wid >> 1, wn = wid & 1;
    const int bm = blockIdx.y * 64, bn = blockIdx.x * 64;
    const int srow = tid >> 2;
    const int soff = (tid & 3) * 8;
    const short* Ag  = (const short*)A;
    const short* Btg = (const short*)Bt;
    const int fr = lane & 15;
    const int kg = (lane >> 4) * 8;
    const int rq = (lane >> 4) * 4;

    f32x4 acc[2][2];
    #pragma unroll
    for (int i = 0; i < 2; ++i)
        #pragma unroll
        for (int j = 0; j < 2; ++j) acc[i][j] = (f32x4){0.f, 0.f, 0.f, 0.f};

    for (int k0 = 0; k0 < E_; k0 += 32) {
        __syncthreads();
        *(bf16x8*)&As[srow][soff] = *(const bf16x8*)&Ag[(size_t)(bm + srow) * E_ + k0 + soff];
        *(bf16x8*)&Bs[srow][soff] = *(const bf16x8*)&Btg[(size_t)(bn + srow) * E_ + k0 + soff];
        __syncthreads();
        bf16x8 af0 = *(const bf16x8*)&As[wm * 32 + fr][kg];
        bf16x8 af1 = *(const bf16x8*)&As[wm * 32 + 16 + fr][kg];
        bf16x8 bf0 = *(const bf16x8*)&Bs[wn * 32 + fr][kg];
        bf16x8 bf1 = *(const bf16x8*)&Bs[wn * 32 + 16 + fr][kg];
        acc[0][0] = __builtin_amdgcn_mfma_f32_16x16x32_bf16(af0, bf0, acc[0][0], 0, 0, 0);
        acc[0][1] = __builtin_amdgcn_mfma_f32_16x16x32_bf16(af0, bf1, acc[0][1], 0, 0, 0);
        acc[1][0] = __builtin_amdgcn_mfma_f32_16x16x32_bf16(af1, bf0, acc[1][0], 0, 0, 0);
        acc[1][1] = __builtin_amdgcn_mfma_f32_16x16x32_bf16(af1, bf1, acc[1][1], 0, 0, 0);
    }

    float m[2][4];
    float msum = 0.f;
    #pragma unroll
    for (int fm = 0; fm < 2; ++fm)
        #pragma unroll
        for (int j = 0; j < 4; ++j) {
            m[fm][j] = smask[bm + wm * 32 + fm * 16 + rq + j];
            msum += m[fm][j];
        }
    float colsum[2];
    #pragma unroll
    for (int fn = 0; fn < 2; ++fn) {
        const float bv = bias[bn + wn * 32 + fn * 16 + fr];
        float s = 0.f;
        #pragma unroll
        for (int fm = 0; fm < 2; ++fm)
            #pragma unroll
            for (int j = 0; j < 4; ++j)
                s = fmaf(selu_f(acc[fm][fn][j] + bv), m[fm][j], s);
        colsum[fn] = s;
    }
    #pragma unroll
    for (int fn = 0; fn < 2; ++fn) {
        colsum[fn] += __shfl_xor(colsum[fn], 16, 64);
        colsum[fn] += __shfl_xor(colsum[fn], 32, 64);
    }
    msum += __shfl_xor(msum, 16, 64);
    msum += __shfl_xor(msum, 32, 64);
    const float inv = 1.0f / fmaxf(msum, 1.0f);
    if (lane < 16) {
        const int g = 2 * blockIdx.y + wm;
        #pragma unroll
        for (int fn = 0; fn < 2; ++fn)
            mrev[(size_t)g * E_ + bn + wn * 32 + fn * 16 + fr] =
                __float2bfloat16(colsum[fn] * inv);
    }
}

// Kernel G2: rev GEMM (BK=64, 8 iters) -> p_batch cols 0..511 + pbar epilogue
// (column means over the in-register 64-row tile). Block 0: user-feat cols
// 512..531 of p_batch and their pbar. grid = 8 blocks.
__global__ __launch_bounds__(256) void k_gemm_rev(
        const __hip_bfloat16* __restrict__ A,   // mrev [64,512]
        const __hip_bfloat16* __restrict__ Bt,  // wT_rev [512,512]
        const float* __restrict__ bias,         // b_rev
        const float* __restrict__ user_feats,   // [64,20]
        const float* __restrict__ user_w,       // [20]
        float* __restrict__ p_batch,            // out [64,532]
        float* __restrict__ pbar)               // out [532] col means
{
    __shared__ short As[64][72];   // 64 x (64 + 8 pad)
    __shared__ short Bs[64][72];
    __shared__ float cs[2][2][2][16];   // [wm][wn][fn][fr]
    __shared__ float ufl[64][U_];       // block 0 only
    const int tid  = threadIdx.x;
    const int wid  = tid >> 6;
    const int lane = tid & 63;
    const int wm = wid >> 1, wn = wid & 1;
    const int bn = blockIdx.x * 64;
    const int fr = lane & 15;
    const int kg = (lane >> 4) * 8;
    const int rq = (lane >> 4) * 4;
    const int srow = tid >> 2;          // 0..63
    const int scol = (tid & 3) * 8;     // 0,8,16,24 (+32 for second chunk)

    // block 0 side-work: user-feat columns + LDS stash for pbar
    if (blockIdx.x == 0 && tid < 64) {
        const int r = tid;
        float ss = 0.f;
        #pragma unroll
        for (int j = 0; j < U_; ++j) {
            const float u = user_feats[r * U_ + j];
            ss = fmaf(u, u, ss);
        }
        const float nrm = fmaxf(sqrtf(ss), 1e-12f);
        #pragma unroll
        for (int j = 0; j < U_; ++j) {
            const float v = user_feats[r * U_ + j] / nrm * user_w[j];
            p_batch[(size_t)r * D_ + E_ + j] = v;
            ufl[r][j] = v;
        }
    }

    const short* Ag  = (const short*)A;
    const short* Btg = (const short*)Bt;

    f32x4 acc[2][2];
    #pragma unroll
    for (int i = 0; i < 2; ++i)
        #pragma unroll
        for (int j = 0; j < 2; ++j) acc[i][j] = (f32x4){0.f, 0.f, 0.f, 0.f};

    for (int k0 = 0; k0 < E_; k0 += 64) {
        __syncthreads();
        *(bf16x8*)&As[srow][scol]      = *(const bf16x8*)&Ag[(size_t)srow * E_ + k0 + scol];
        *(bf16x8*)&As[srow][scol + 32] = *(const bf16x8*)&Ag[(size_t)srow * E_ + k0 + scol + 32];
        *(bf16x8*)&Bs[srow][scol]      = *(const bf16x8*)&Btg[(size_t)(bn + srow) * E_ + k0 + scol];
        *(bf16x8*)&Bs[srow][scol + 32] = *(const bf16x8*)&Btg[(size_t)(bn + srow) * E_ + k0 + scol + 32];
        __syncthreads();
        #pragma unroll
        for (int ks = 0; ks < 64; ks += 32) {
            bf16x8 af0 = *(const bf16x8*)&As[wm * 32 + fr][ks + kg];
            bf16x8 af1 = *(const bf16x8*)&As[wm * 32 + 16 + fr][ks + kg];
            bf16x8 bf0 = *(const bf16x8*)&Bs[wn * 32 + fr][ks + kg];
            bf16x8 bf1 = *(const bf16x8*)&Bs[wn * 32 + 16 + fr][ks + kg];
            acc[0][0] = __builtin_amdgcn_mfma_f32_16x16x32_bf16(af0, bf0, acc[0][0], 0, 0, 0);
            acc[0][1] = __builtin_amdgcn_mfma_f32_16x16x32_bf16(af0, bf1, acc[0][1], 0, 0, 0);
            acc[1][0] = __builtin_amdgcn_mfma_f32_16x16x32_bf16(af1, bf0, acc[1][0], 0, 0, 0);
            acc[1][1] = __builtin_amdgcn_mfma_f32_16x16x32_bf16(af1, bf1, acc[1][1], 0, 0, 0);
        }
    }

    // epilogue: write p_batch + per-column sums (wave covers 32 rows at wm half)
    float colsum[2] = {0.f, 0.f};
    #pragma unroll
    for (int fm = 0; fm < 2; ++fm) {
        #pragma unroll
        for (int fn = 0; fn < 2; ++fn) {
            const int col = bn + wn * 32 + fn * 16 + fr;
            const float bv = bias[col];
            #pragma unroll
            for (int j = 0; j < 4; ++j) {
                const int row = wm * 32 + fm * 16 + rq + j;
                const float val = selu_f(acc[fm][fn][j] + bv);
                p_batch[(size_t)row * D_ + col] = val;
                colsum[fn] += val;
            }
        }
    }
    #pragma unroll
    for (int fn = 0; fn < 2; ++fn) {
        colsum[fn] += __shfl_xor(colsum[fn], 16, 64);
        colsum[fn] += __shfl_xor(colsum[fn], 32, 64);
    }
    if (lane < 16) {
        cs[wm][wn][0][fr] = colsum[0];
        cs[wm][wn][1][fr] = colsum[1];
    }
    __syncthreads();
    if (tid < 64) {
        const int wn2 = tid >> 5, fn2 = (tid >> 4) & 1, fr2 = tid & 15;
        const float s = cs[0][wn2][fn2][fr2] + cs[1][wn2][fn2][fr2];
        pbar[bn + wn2 * 32 + fn2 * 16 + fr2] = s * (1.0f / 64.0f);
    }
    if (blockIdx.x == 0 && tid < U_) {
        float s = 0.f;
        #pragma unroll 16
        for (int r = 0; r < 64; ++r) s += ufl[r][tid];
        pbar[E_ + tid] = s * (1.0f / 64.0f);
    }
}

// Kernel D (fused): partial GEMV tiles from precomputed pbar; last block
// finalizes with parallel hn-GEMV + r_stars. grid (5,5).
__global__ __launch_bounds__(256) void k_prod_fused(
        const float* __restrict__ pbar_g,   // [532]
        const float* __restrict__ p_batch,  // [64,532]
        const float* __restrict__ w_prod,
        const float* __restrict__ b_prod,
        const float* __restrict__ w_pff,
        const float* __restrict__ b_pff,
        const float* __restrict__ w_rff,
        const float* __restrict__ b_rff,
        float* __restrict__ part,
        int* __restrict__ dcount,
        float* __restrict__ out_p,
        float* __restrict__ out_r)
{
    __shared__ float pb[PCHUNK];
    __shared__ float red[2][PCHUNK];
    const int cg = blockIdx.x, kg = blockIdx.y;
    const int tid = threadIdx.x;
    const int cl = tid & (PCHUNK - 1);
    const int h  = tid >> 7;
    const int k0 = kg * PCHUNK;
    const int klen = min(PCHUNK, D_ - k0);

    if (tid < klen) pb[tid] = pbar_g[k0 + tid];
    __syncthreads();

    const int c = cg * PCHUNK + cl;
    float acc = 0.f;
    if (c < D_) {
        const int jb = h * 64;
        const int je = min(jb + 64, klen);
        for (int j = jb; j < je; ++j)
            acc = fmaf(pb[j], w_prod[(size_t)(k0 + j) * D_ + c], acc);
    }
    red[h][cl] = acc;
    __syncthreads();
    if (h == 0 && c < D_) part[kg * D_ + c] = red[0][cl] + red[1][cl];

    __threadfence();
    __shared__ int is_last;
    if (tid == 0) is_last = (atomicAdd(dcount, 1) == NCG * NKG - 1);
    __syncthreads();
    if (!is_last) return;
    __threadfence();

    __shared__ float hn[D_];
    __shared__ float rred[4][64];
    __shared__ float ppart[L_][28];
    for (int cc = tid; cc < D_; cc += 256) {
        float s = b_prod[cc];
        #pragma unroll
        for (int g = 0; g < NKG; ++g) s += part[g * D_ + cc];
        hn[cc] = selu_f(s);
    }
    __syncthreads();
    // p_stars: 9 outputs x 28 k-chunks
    if (tid < L_ * 28) {
        const int o = tid / 28, ii = tid % 28;
        float s = 0.f;
        for (int k = ii; k < D_; k += 28)
            s = fmaf(hn[k], w_pff[(size_t)k * L_ + o], s);
        ppart[o][ii] = s;
    }
    // r_stars partials: 4 k-quarters x 64 reviews
    {
        const int r = tid & 63, q = tid >> 6;
        float pr = 0.f;
        for (int k = q * 133; k < (q + 1) * 133; ++k)
            pr = fmaf(p_batch[(size_t)r * D_ + k], w_rff[k], pr);
        rred[q][r] = pr;
    }
    __syncthreads();
    if (tid < L_) {
        float s = 0.f;
        #pragma unroll
        for (int ii = 0; ii < 28; ++ii) s += ppart[tid][ii];
        out_p[tid] = selu_f(s + b_pff[tid]);
    }
    if (tid < 64)
        out_r[tid] = selu_f(rred[0][tid] + rred[1][tid] + rred[2][tid] + rred[3][tid]
                            + b_rff[0]);
}

extern "C" void kernel_launch(void* const* d_in, const int* in_sizes, int n_in,
                              void* d_out, int out_size, void* d_ws, size_t ws_size,
                              hipStream_t stream) {
    const int*   inputs     = (const int*)  d_in[0];
    const float* user_feats = (const float*)d_in[1];
    const float* emb        = (const float*)d_in[2];
    const float* w_sent     = (const float*)d_in[3];
    const float* b_sent     = (const float*)d_in[4];
    const float* w_rev      = (const float*)d_in[5];
    const float* b_rev      = (const float*)d_in[6];
    const float* w_prod     = (const float*)d_in[7];
    const float* b_prod     = (const float*)d_in[8];
    const float* w_rff      = (const float*)d_in[9];
    const float* b_rff      = (const float*)d_in[10];
    const float* w_pff      = (const float*)d_in[11];
    const float* b_pff      = (const float*)d_in[12];
    const float* user_w     = (const float*)d_in[13];
    float* out = (float*)d_out;   // [0..8] p_stars, [9..72] r_stars

    float* ws = (float*)d_ws;
    __hip_bfloat16* sent_bf = (__hip_bfloat16*)(ws);            // 2048*512 bf16
    __hip_bfloat16* wT      = (__hip_bfloat16*)(ws + 524288);   // 2*512*512 bf16
    __hip_bfloat16* mrev    = (__hip_bfloat16*)(ws + 786432);   // 64*512 bf16
    float* smask   = ws + 802816;    // 2048
    float* p_batch = ws + 804864;    // 64*532
    float* part    = ws + 838912;    // 5*532
    float* pbar_ws = ws + 841600;    // 544
    int*   dcount  = (int*)(ws + 842144);

    k_fused_A<<<NSENT + 512, 256, 0, stream>>>(inputs, emb, w_sent, w_rev,
                                               sent_bf, wT, smask, dcount);
    k_gemm_sent_mean<<<dim3(E_ / 64, NSENT / 64), 256, 0, stream>>>(
        sent_bf, wT, b_sent, smask, mrev);
    k_gemm_rev<<<dim3(8, 1), 256, 0, stream>>>(
        mrev, wT + (size_t)E_ * E_, b_rev, user_feats, user_w, p_batch, pbar_ws);
    k_prod_fused<<<dim3(NCG, NKG), 256, 0, stream>>>(
        pbar_ws, p_batch, w_prod, b_prod, w_pff, b_pff, w_rff, b_rff,
        part, dcount, out, out + L_);
}